// Round 15
// baseline (114.124 us; speedup 1.0000x reference)
//
#include <hip/hip_runtime.h>

// Problem constants
static constexpr int NQ    = 12;
static constexpr int DEPTH = 4;
static constexpr int LAT   = 512;
static constexpr int FAST  = DEPTH * NQ;   // 48
static constexpr float DECAY = 0.9f;
static constexpr int P     = 68;           // row pitch (floats): 272 B, 16B-aligned

// ONE WAVE = TWO batch elements (A,B), separate LDS buffers (r13 skeleton).
// L orientation: i = (lane<<6) | r (wires 0..5 lane bits, 6..11 reg bits); T swaps.
// Layer = RY(12) ∘ CNOT-chain(0..10); sigma^-1: bit_p = j_p ^ j_{p+1}.
// Pass 1: b32 row-writes + sigma-and-transpose-folded b32 reads (verified).
// Pass 2: b32 scatter-writes + b128 row-reads (quad lands in consecutive regs,
// rename-free). ALL math is scalar v_fma_f32: r14 post-mortem found ~4x VALU
// inflation from v_pk_*_f32 / b128-write register-pair marshaling (packed ops
// need consecutive even-aligned VGPRs; scattered scalars force v_mov chains).

// scalar butterfly, stride S, on half [B, B+32)
template<int S, int B>
__device__ __forceinline__ void bfly_half(float (&v)[64], float c, float s) {
    #pragma unroll
    for (int r0 = B; r0 < B + 32; r0++) {
        if ((r0 & S) == 0) {
            float a = v[r0], b = v[r0 + S];
            v[r0]     = c * a - s * b;
            v[r0 + S] = s * a + c * b;
        }
    }
}

// wires with strides 16,8,4,2,1 on half [B, B+32)
template<int B>
__device__ __forceinline__ void ry5_half(float (&v)[64], const float* lc, const float* ls) {
    bfly_half<16, B>(v, lc[0], ls[0]);
    bfly_half<8,  B>(v, lc[1], ls[1]);
    bfly_half<4,  B>(v, lc[2], ls[2]);
    bfly_half<2,  B>(v, lc[3], ls[3]);
    bfly_half<1,  B>(v, lc[4], ls[4]);
}

// stride-32 wire across halves (applied last; commutes with the others)
__device__ __forceinline__ void bfly32(float (&v)[64], float c, float s) {
    #pragma unroll
    for (int r0 = 0; r0 < 32; r0++) {
        float a = v[r0], b = v[r0 + 32];
        v[r0]      = c * a - s * b;
        v[r0 + 32] = s * a + c * b;
    }
}

// 6-wire block for one orientation: lc[0]/ls[0] = stride-32 wire
__device__ __forceinline__ void ry6(float (&v)[64], const float* lc, const float* ls) {
    ry5_half<0>(v, lc + 1, ls + 1);
    ry5_half<32>(v, lc + 1, ls + 1);
    bfly32(v, lc[0], ls[0]);
}

// pass-1: scalar row writes; sigma+transpose-folded scalar reads (verified r5-r14)
__device__ __forceinline__ void pass1(float (&v)[64], float* X, int lane, int A0, int A1) {
    #pragma unroll
    for (int r = 0; r < 64; r++) X[lane * P + r] = v[r];
    #pragma unroll
    for (int r = 0; r < 64; r++) {
        const int g = r ^ (r >> 1);                 // compile-time imm offset
        v[r] = X[g * P + ((r & 1) ? A1 : A0)];
    }
}

// pass-2: scalar scatter writes; b128 row reads (consecutive-quad dst, rename-free)
__device__ __forceinline__ void pass2(float (&v)[64], float* X, int lane) {
    #pragma unroll
    for (int q = 0; q < 64; q++) X[q * P + lane] = v[q];   // addr = lane*4 + imm
    #pragma unroll
    for (int k = 0; k < 16; k++) {
        float4 t = *(const float4*)&X[lane * P + 4 * k];
        v[4 * k]     = t.x;  v[4 * k + 1] = t.y;
        v[4 * k + 2] = t.z;  v[4 * k + 3] = t.w;
    }
}

// closed-form product state from the 12 initial RYs (verified r2-r14)
__device__ __forceinline__ void init_state(float (&v)[64], const float (&xa)[NQ], int lane) {
    float g0[NQ], g1[NQ];
    #pragma unroll
    for (int w = 0; w < NQ; w++) {
        float hh = 0.5f * xa[w];
        float c = __cosf(hh), s = __sinf(hh);
        g0[w] = (c - s) * 0.70710678118654752f;
        g1[w] = (c + s) * 0.70710678118654752f;
    }
    float L = 1.0f;
    #pragma unroll
    for (int w = 0; w < 6; w++)
        L *= ((lane >> (5 - w)) & 1) ? g1[w] : g0[w];
    v[0] = L;
    #pragma unroll
    for (int w = 6; w < NQ; w++) {
        const int S = 1 << (11 - w);
        #pragma unroll
        for (int r = 0; r < 64; r += 2 * S) {
            v[r + S] = v[r] * g1[w];
            v[r]     = v[r] * g0[w];
        }
    }
}

__global__ __launch_bounds__(64, 1)
void fwp_kernel(const float* __restrict__ x_t,
                const float* __restrict__ fast_prev,
                const float* __restrict__ W_enc,
                const float* __restrict__ b_enc,
                const float* __restrict__ W_upd,
                const float* __restrict__ b_upd,
                const float* __restrict__ W_ro,
                const float* __restrict__ b_ro,
                float* __restrict__ out_y,
                float* __restrict__ out_fast) {
    const int lane = threadIdx.x;          // block = one wave
    const int eA   = 2 * blockIdx.x;
    const int eB   = eA + 1;

    __shared__ __align__(16) float XA[64 * P];   // 17408 B
    __shared__ __align__(16) float XB[64 * P];   // 17408 B
    __shared__ float cA[FAST], sA_[FAST], cB[FAST], sB_[FAST];

    float* latA = XA;   // latents carved from circuit buffers (dead later)
    float* latB = XB;

    // ---- x rows (wave-uniform scalar loads, verified r7) ----
    float xaA[NQ], xaB[NQ];
    #pragma unroll
    for (int k = 0; k < NQ; k++) {
        xaA[k] = x_t[eA * NQ + k];
        xaB[k] = x_t[eB * NQ + k];
    }

    // ---- Phase A: lane owns latents j = 8*lane..8*lane+7 (verified r13) ----
    {
        const float4* we = (const float4*)(W_enc + lane * 8 * NQ);  // 8 rows, 384 B
        float lA[8], lB[8];
        #pragma unroll
        for (int t = 0; t < 8; t++) {
            float4 a0 = we[3 * t], a1 = we[3 * t + 1], a2 = we[3 * t + 2];
            float be = b_enc[8 * lane + t];
            float sAv = be
                + a0.x * xaA[0] + a0.y * xaA[1] + a0.z * xaA[2]  + a0.w * xaA[3]
                + a1.x * xaA[4] + a1.y * xaA[5] + a1.z * xaA[6]  + a1.w * xaA[7]
                + a2.x * xaA[8] + a2.y * xaA[9] + a2.z * xaA[10] + a2.w * xaA[11];
            float sBv = be
                + a0.x * xaB[0] + a0.y * xaB[1] + a0.z * xaB[2]  + a0.w * xaB[3]
                + a1.x * xaB[4] + a1.y * xaB[5] + a1.z * xaB[6]  + a1.w * xaB[7]
                + a2.x * xaB[8] + a2.y * xaB[9] + a2.z * xaB[10] + a2.w * xaB[11];
            lA[t] = tanhf(sAv);
            lB[t] = tanhf(sBv);
        }
        #pragma unroll
        for (int t = 0; t < 8; t++) {
            latA[8 * lane + t] = lA[t];
            latB[8 * lane + t] = lB[t];
        }
    }

    // ---- Phase B: 48 angles per element; W_upd row loaded once ----
    if (lane < FAST) {
        const float4* wr = (const float4*)(W_upd + lane * LAT);
        const float4* la = (const float4*)(latA);
        const float4* lb = (const float4*)(latB);
        float base = b_upd[lane];
        float sAv = base, sBv = base;
        #pragma unroll 8
        for (int j = 0; j < LAT / 4; j++) {
            float4 w4 = wr[j];
            float4 a4 = la[j];   // uniform -> broadcast
            float4 b4 = lb[j];
            sAv += w4.x * a4.x + w4.y * a4.y + w4.z * a4.z + w4.w * a4.w;
            sBv += w4.x * b4.x + w4.y * b4.y + w4.z * b4.z + w4.w * b4.w;
        }
        float angA = DECAY * fast_prev[eA * FAST + lane] + sAv;
        float angB = DECAY * fast_prev[eB * FAST + lane] + sBv;
        out_fast[eA * FAST + lane] = angA;
        out_fast[eB * FAST + lane] = angB;
        cA[lane]  = __cosf(0.5f * angA);
        sA_[lane] = __sinf(0.5f * angA);
        cB[lane]  = __cosf(0.5f * angB);
        sB_[lane] = __sinf(0.5f * angB);
    }

    // ---- product states ----
    float vA[64], vB[64];
    init_state(vA, xaA, lane);
    init_state(vB, xaB, lane);

    const int A0 = ((lane ^ (lane >> 1)) & 31) | (lane & 32);
    const int A1 = A0 ^ 32;

    // ---- 4 layers (r13 per-element ordering; scalar math throughout) ----
    #pragma unroll 1
    for (int layer = 0; layer < DEPTH; layer++) {
        float lcA[NQ], lsA[NQ], lcB[NQ], lsB[NQ];
        #pragma unroll
        for (int w = 0; w < NQ; w++) {
            lcA[w] = cA[layer * NQ + w];   lsA[w] = sA_[layer * NQ + w];
            lcB[w] = cB[layer * NQ + w];   lsB[w] = sB_[layer * NQ + w];
        }

        // pass 1 (sigma + L->T), wires 0..5 in T (stride-32 wire = wire 0)
        pass1(vA, XA, lane, A0, A1);
        ry6(vA, lcA, lsA);
        pass1(vB, XB, lane, A0, A1);
        ry6(vB, lcB, lsB);
        // pass 2 (transpose back), wires 6..11 in L (stride-32 wire = wire 6)
        pass2(vA, XA, lane);
        ry6(vA, lcA + 6, lsA + 6);
        pass2(vB, XB, lane);
        ry6(vB, lcB + 6, lsB + 6);
    }

    // ---- Z expectations folded into readout, both elements (verified r9) ----
    float wro[NQ];
    #pragma unroll
    for (int w = 0; w < NQ; w++) wro[w] = W_ro[w];
    float sl = 0.0f;
    #pragma unroll
    for (int w = 0; w < 6; w++)
        sl += ((lane >> (5 - w)) & 1) ? -wro[w] : wro[w];

    float totA = 0.0f, pwA[6] = {0,0,0,0,0,0};
    float totB = 0.0f, pwB[6] = {0,0,0,0,0,0};
    #pragma unroll
    for (int r = 0; r < 64; r++) {
        float pA = vA[r] * vA[r];
        float pB = vB[r] * vB[r];
        totA += pA;  totB += pB;
        pwA[0] += (r & 32) ? -pA : pA;  pwB[0] += (r & 32) ? -pB : pB;
        pwA[1] += (r & 16) ? -pA : pA;  pwB[1] += (r & 16) ? -pB : pB;
        pwA[2] += (r & 8)  ? -pA : pA;  pwB[2] += (r & 8)  ? -pB : pB;
        pwA[3] += (r & 4)  ? -pA : pA;  pwB[3] += (r & 4)  ? -pB : pB;
        pwA[4] += (r & 2)  ? -pA : pA;  pwB[4] += (r & 2)  ? -pB : pB;
        pwA[5] += (r & 1)  ? -pA : pA;  pwB[5] += (r & 1)  ? -pB : pB;
    }
    float yA = sl * totA, yB = sl * totB;
    #pragma unroll
    for (int k = 0; k < 6; k++) {
        yA += wro[6 + k] * pwA[k];
        yB += wro[6 + k] * pwB[k];
    }
    #pragma unroll
    for (int m = 32; m >= 1; m >>= 1) {
        yA += __shfl_xor(yA, m, 64);
        yB += __shfl_xor(yB, m, 64);
    }
    if (lane == 0) {
        float br = b_ro[0];
        out_y[eA] = yA + br;
        out_y[eB] = yB + br;
    }
}

extern "C" void kernel_launch(void* const* d_in, const int* in_sizes, int n_in,
                              void* d_out, int out_size, void* d_ws, size_t ws_size,
                              hipStream_t stream) {
    const float* x_t       = (const float*)d_in[0];
    const float* fast_prev = (const float*)d_in[1];
    const float* W_enc     = (const float*)d_in[2];
    const float* b_enc     = (const float*)d_in[3];
    const float* W_upd     = (const float*)d_in[4];
    const float* b_upd     = (const float*)d_in[5];
    const float* W_ro      = (const float*)d_in[6];
    const float* b_ro      = (const float*)d_in[7];
    float* out = (float*)d_out;

    // 1024 blocks x 1 wave, 2 batch elements per wave
    fwp_kernel<<<1024, 64, 0, stream>>>(x_t, fast_prev, W_enc, b_enc,
                                        W_upd, b_upd, W_ro, b_ro,
                                        out /*y*/, out + 2048 /*fast_next*/);
}